// Round 1
// baseline (526.172 us; speedup 1.0000x reference)
//
#include <hip/hip_runtime.h>

typedef __bf16 bf16x8 __attribute__((ext_vector_type(8)));
typedef __bf16 bf16x4v __attribute__((ext_vector_type(4)));
typedef float f32x4 __attribute__((ext_vector_type(4)));

#define LDS_ASYNC16(g, l)                                            \
  __builtin_amdgcn_global_load_lds(                                  \
      (__attribute__((address_space(1))) void*)(g),                  \
      (__attribute__((address_space(3))) void*)(l), 16, 0, 0)

// ---------------------------------------------------------------------------
// cast fp32 -> bf16, 4 elems/thread
__global__ void cast_bf16(const float* __restrict__ x, __bf16* __restrict__ y,
                          int n4) {
  int i = blockIdx.x * 256 + threadIdx.x;
  if (i < n4) {
    float4 v = ((const float4*)x)[i];
    bf16x4v o;
    o[0] = (__bf16)v.x; o[1] = (__bf16)v.y; o[2] = (__bf16)v.z; o[3] = (__bf16)v.w;
    ((bf16x4v*)y)[i] = o;
  }
}

// ---------------------------------------------------------------------------
// transpose+cast: src (K x N) fp32 row-major -> dst (N x K) bf16 row-major
// grid: (K/64, N/64), 256 threads
__global__ void wtrans(const float* __restrict__ src, int srcld,
                       __bf16* __restrict__ dst, int dstld) {
  __shared__ float tile[64][65];
  int k0 = blockIdx.x * 64, n0 = blockIdx.y * 64;
  int tl = threadIdx.x >> 6, c = threadIdx.x & 63;
#pragma unroll
  for (int rr = 0; rr < 16; ++rr) {
    int k = rr * 4 + tl;
    tile[k][c] = src[(size_t)(k0 + k) * srcld + n0 + c];
  }
  __syncthreads();
#pragma unroll
  for (int rr = 0; rr < 16; ++rr) {
    int n = rr * 4 + tl;
    dst[(size_t)(n0 + n) * dstld + k0 + c] = (__bf16)tile[c][n];
  }
}

// ---------------------------------------------------------------------------
// m97-style bf16 GEMM: C(MxN) = A(MxK) * B^T where B is (N x K) row-major.
// 128x128 tile, BK=32, 4 waves (2x2), each wave 4x4 16x16x32 MFMA tiles.
template <int OUTBF16>
__global__ __launch_bounds__(256) void gemm_bt(const __bf16* __restrict__ A,
                                               const __bf16* __restrict__ B,
                                               void* __restrict__ Cout, int M,
                                               int N, int K) {
  __shared__ __bf16 As[128 * 32];
  __shared__ __bf16 Bs[128 * 32];
  int tid = threadIdx.x;
  int wave = tid >> 6, lane = tid & 63;
  int quad = lane >> 4, l16 = lane & 15;
  int wm = (wave & 1) * 64, wn = (wave >> 1) * 64;
  int tm = blockIdx.y * 128, tn = blockIdx.x * 128;

  f32x4 acc[4][4] = {};

  int srow = tid >> 2;          // 0..63
  int scol = (tid & 3) * 8;     // 0,8,16,24
  const __bf16* gA = A + (size_t)(tm + srow) * K + scol;
  const __bf16* gB = B + (size_t)(tn + srow) * K + scol;
  __bf16* lA0 = As + wave * 512;
  __bf16* lA1 = As + 2048 + wave * 512;
  __bf16* lB0 = Bs + wave * 512;
  __bf16* lB1 = Bs + 2048 + wave * 512;
  size_t stepA = (size_t)64 * K;

  for (int k0 = 0; k0 < K; k0 += 32) {
    LDS_ASYNC16(gA, lA0);
    LDS_ASYNC16(gA + stepA, lA1);
    LDS_ASYNC16(gB, lB0);
    LDS_ASYNC16(gB + stepA, lB1);
    gA += 32;
    gB += 32;
    __syncthreads();  // drains vmcnt -> LDS data visible
    bf16x8 af[4], bfr[4];
#pragma unroll
    for (int mt = 0; mt < 4; ++mt)
      af[mt] = *(const bf16x8*)(As + (wm + mt * 16 + l16) * 32 + quad * 8);
#pragma unroll
    for (int nt = 0; nt < 4; ++nt)
      bfr[nt] = *(const bf16x8*)(Bs + (wn + nt * 16 + l16) * 32 + quad * 8);
#pragma unroll
    for (int mt = 0; mt < 4; ++mt)
#pragma unroll
      for (int nt = 0; nt < 4; ++nt)
        acc[mt][nt] = __builtin_amdgcn_mfma_f32_16x16x32_bf16(
            af[mt], bfr[nt], acc[mt][nt], 0, 0, 0);
    __syncthreads();
  }
  int r0 = tm + wm + quad * 4;
  int c0 = tn + wn + l16;
#pragma unroll
  for (int mt = 0; mt < 4; ++mt)
#pragma unroll
    for (int nt = 0; nt < 4; ++nt)
#pragma unroll
      for (int r = 0; r < 4; ++r) {
        size_t idx = (size_t)(r0 + mt * 16 + r) * N + (c0 + nt * 16);
        if (OUTBF16)
          ((__bf16*)Cout)[idx] = (__bf16)acc[mt][nt][r];
        else
          ((float*)Cout)[idx] = acc[mt][nt][r];
      }
}

// ---------------------------------------------------------------------------
// RoPE on Q: qkv cols [0,2048) -> Qr (b,H,t,64) bf16
__global__ void rope_q_kernel(const __bf16* __restrict__ qkv,
                              __bf16* __restrict__ Qr) {
  int n = blockIdx.x * 256 + threadIdx.x;
  int i = n & 31, h = (n >> 5) & 31, t = (n >> 10) & 1023, b = n >> 20;
  const __bf16* src = qkv + (size_t)(b * 1024 + t) * 3072 + h * 64;
  float x1 = (float)src[i], x2 = (float)src[i + 32];
  // inv_freq = 10000^(-i/32) = exp(-i * ln(10000)/32)
  float ang = (float)t * expf((float)i * -0.28782313662425572f);
  float cv = cosf(ang), sv = sinf(ang);
  float o1 = x1 * cv - x2 * sv;
  float o2 = x2 * cv + x1 * sv;
  __bf16* dst = Qr + (((size_t)b * 32 + h) * 1024 + t) * 64;
  dst[i] = (__bf16)o1;
  dst[i + 32] = (__bf16)o2;
}

// RoPE on K + per-key squared norm (RoPE preserves norms; compute from the
// bf16-rounded values so scores stay exactly conformal in the rounded k).
__global__ void rope_k_kernel(const __bf16* __restrict__ qkv,
                              __bf16* __restrict__ Kr,
                              float* __restrict__ knsq) {
  int n = blockIdx.x * 256 + threadIdx.x;
  int i = n & 31, kvh = (n >> 5) & 7, t = (n >> 8) & 1023, b = n >> 18;
  const __bf16* src = qkv + (size_t)(b * 1024 + t) * 3072 + 2048 + kvh * 64;
  float x1 = (float)src[i], x2 = (float)src[i + 32];
  float ang = (float)t * expf((float)i * -0.28782313662425572f);
  float cv = cosf(ang), sv = sinf(ang);
  float o1 = x1 * cv - x2 * sv;
  float o2 = x2 * cv + x1 * sv;
  __bf16 b1 = (__bf16)o1, b2 = (__bf16)o2;
  float f1 = (float)b1, f2 = (float)b2;
  float nrm = f1 * f1 + f2 * f2;
#pragma unroll
  for (int off = 1; off < 32; off <<= 1) nrm += __shfl_xor(nrm, off, 64);
  __bf16* dst = Kr + (((size_t)b * 8 + kvh) * 1024 + t) * 64;
  dst[i] = b1;
  dst[i + 32] = b2;
  if (i == 0) knsq[((size_t)b * 8 + kvh) * 1024 + t] = nrm;
}

// ---------------------------------------------------------------------------
// V transpose: qkv cols [2560,3072) -> VT (b,KV,64,t) bf16
// grid: (t/64, b*KV)
__global__ void vtrans(const __bf16* __restrict__ qkv,
                       __bf16* __restrict__ VT) {
  __shared__ __bf16 tile[64][65];
  int tt = blockIdx.x, bkv = blockIdx.y;
  int b = bkv >> 3, kv = bkv & 7;
  int tl = threadIdx.x >> 6, d = threadIdx.x & 63;
#pragma unroll
  for (int rr = 0; rr < 16; ++rr) {
    int t_local = rr * 4 + tl;
    tile[t_local][d] =
        qkv[(size_t)(b * 1024 + tt * 64 + t_local) * 3072 + 2560 + kv * 64 + d];
  }
  __syncthreads();
#pragma unroll
  for (int rr = 0; rr < 16; ++rr) {
    int d_out = rr * 4 + tl;
    VT[((size_t)(b * 8 + kv) * 64 + d_out) * 1024 + tt * 64 + d] =
        tile[d][d_out];
  }
}

// ---------------------------------------------------------------------------
// Flash attention with conformal scores:
//   s = (q.k - 0.5*|k|^2)/8   (the -0.5|q|^2 row-constant cancels in softmax)
// Q-tile 64 rows/block; wave = 16 rows; K-tiles of 128 keys.
// grid: (16 qtiles, 32 heads, 4 batch), 256 threads.
__global__ __launch_bounds__(256) void attn_kernel(
    const __bf16* __restrict__ Q, const __bf16* __restrict__ Kc,
    const __bf16* __restrict__ VT, const float* __restrict__ knsq,
    __bf16* __restrict__ Y) {
  const int T = 1024;
  int qt = blockIdx.x, h = blockIdx.y, b = blockIdx.z;
  int kv = h >> 2;
  int wave = threadIdx.x >> 6, lane = threadIdx.x & 63;
  int quad = lane >> 4, l16 = lane & 15;
  int q0 = qt * 64;
  int qrow0 = q0 + wave * 16;
  __shared__ __bf16 Plds[4][16 * 136];  // +8 pad breaks bank aliasing

  const __bf16* Qb = Q + (((size_t)b * 32 + h) * T + qrow0) * 64;
  const __bf16* Kb = Kc + ((size_t)b * 8 + kv) * T * 64;
  const __bf16* Vb = VT + ((size_t)b * 8 + kv) * 64 * T;
  const float* nb = knsq + ((size_t)b * 8 + kv) * T;

  bf16x8 qf[2];
#pragma unroll
  for (int ki = 0; ki < 2; ++ki)
    qf[ki] = *(const bf16x8*)(Qb + (size_t)l16 * 64 + ki * 32 + quad * 8);

  f32x4 o[4] = {};
  float mrow[4], lrow[4];
#pragma unroll
  for (int r = 0; r < 4; ++r) {
    mrow[r] = -1e30f;
    lrow[r] = 0.f;
  }

  int ktiles = (q0 + 63) / 128 + 1;
  for (int j = 0; j < ktiles; ++j) {
    int k0 = j * 128;
    // ---- S = Q K^T (16 MFMA)
    f32x4 s[8] = {};
#pragma unroll
    for (int ki = 0; ki < 2; ++ki)
#pragma unroll
      for (int nt = 0; nt < 8; ++nt) {
        bf16x8 kf = *(const bf16x8*)(Kb + (size_t)(k0 + nt * 16 + l16) * 64 +
                                     ki * 32 + quad * 8);
        s[nt] =
            __builtin_amdgcn_mfma_f32_16x16x32_bf16(qf[ki], kf, s[nt], 0, 0, 0);
      }
    // ---- bias + causal mask + row max
    float sv[8][4];
    float mx[4] = {-1e30f, -1e30f, -1e30f, -1e30f};
#pragma unroll
    for (int nt = 0; nt < 8; ++nt) {
      int col = k0 + nt * 16 + l16;
      float bias = -0.5f * nb[col];
#pragma unroll
      for (int r = 0; r < 4; ++r) {
        int rowq = qrow0 + quad * 4 + r;
        float x = (s[nt][r] + bias) * 0.125f;
        x = (col <= rowq) ? x : -1e30f;
        sv[nt][r] = x;
        mx[r] = fmaxf(mx[r], x);
      }
    }
#pragma unroll
    for (int off = 1; off < 16; off <<= 1)
#pragma unroll
      for (int r = 0; r < 4; ++r)
        mx[r] = fmaxf(mx[r], __shfl_xor(mx[r], off, 64));
    float alpha[4];
#pragma unroll
    for (int r = 0; r < 4; ++r) {
      float mnew = fmaxf(mrow[r], mx[r]);
      alpha[r] = __expf(mrow[r] - mnew);
      mrow[r] = mnew;
    }
    // ---- P = exp(s - m), row sums, stash P in LDS (A-layout source)
    float ls[4] = {0.f, 0.f, 0.f, 0.f};
#pragma unroll
    for (int nt = 0; nt < 8; ++nt)
#pragma unroll
      for (int r = 0; r < 4; ++r) {
        float p = __expf(sv[nt][r] - mrow[r]);
        ls[r] += p;
        Plds[wave][(quad * 4 + r) * 136 + nt * 16 + l16] = (__bf16)p;
      }
#pragma unroll
    for (int off = 1; off < 16; off <<= 1)
#pragma unroll
      for (int r = 0; r < 4; ++r) ls[r] += __shfl_xor(ls[r], off, 64);
#pragma unroll
    for (int r = 0; r < 4; ++r) lrow[r] = lrow[r] * alpha[r] + ls[r];
#pragma unroll
    for (int ot = 0; ot < 4; ++ot)
#pragma unroll
      for (int r = 0; r < 4; ++r) o[ot][r] *= alpha[r];
    // ---- O += P V  (16 MFMA); P re-read in A-layout, V^T frags from global
#pragma unroll
    for (int ki = 0; ki < 4; ++ki) {
      bf16x8 pf = *(const bf16x8*)(&Plds[wave][l16 * 136 + ki * 32 + quad * 8]);
#pragma unroll
      for (int ot = 0; ot < 4; ++ot) {
        bf16x8 vf = *(const bf16x8*)(Vb + (size_t)(ot * 16 + l16) * T + k0 +
                                     ki * 32 + quad * 8);
        o[ot] = __builtin_amdgcn_mfma_f32_16x16x32_bf16(pf, vf, o[ot], 0, 0, 0);
      }
    }
  }
  // ---- epilogue: Y (b,t,H,64) bf16
#pragma unroll
  for (int ot = 0; ot < 4; ++ot)
#pragma unroll
    for (int r = 0; r < 4; ++r) {
      int rowq = qrow0 + quad * 4 + r;
      int col = ot * 16 + l16;
      Y[(((size_t)b * T + rowq) * 32 + h) * 64 + col] =
          (__bf16)(o[ot][r] / lrow[r]);
    }
}

// ---------------------------------------------------------------------------
extern "C" void kernel_launch(void* const* d_in, const int* in_sizes, int n_in,
                              void* d_out, int out_size, void* d_ws,
                              size_t ws_size, hipStream_t stream) {
  const float* x = (const float*)d_in[0];
  const float* Wq = (const float*)d_in[1];
  const float* Wk = (const float*)d_in[2];
  const float* Wv = (const float*)d_in[3];
  const float* Wo = (const float*)d_in[4];
  float* out = (float*)d_out;

  char* ws = (char*)d_ws;
  // region A: x_bf16 (16.8MB), later reused as Qr (same size)
  __bf16* xb = (__bf16*)(ws);
  // region B: W1T 3072x2048 bf16 (12.6MB), later reused as WoT (8.4MB)
  __bf16* W1T = (__bf16*)(ws + 16777216);
  // region C: qkv 4096x3072 bf16 (25.2MB), later reused as y (16.8MB)
  __bf16* qkv = (__bf16*)(ws + 16777216 + 12582912);
  // region D: Kr (4.2MB) + VT (4.2MB) + knsq (128KB)
  char* d4 = ws + 16777216 + 12582912 + 25165824;
  __bf16* Kr = (__bf16*)(d4);
  __bf16* VT = (__bf16*)(d4 + 4194304);
  float* nsq = (float*)(d4 + 8388608);
  __bf16* Qr = xb;    // after gemm1, x_bf16 is dead
  __bf16* WoT = W1T;  // after gemm1, W1T is dead
  __bf16* y = qkv;    // after rope/vtrans, qkv is dead

  // 1. casts / weight transposes
  cast_bf16<<<8192, 256, 0, stream>>>(x, xb, 2097152);
  wtrans<<<dim3(32, 32), 256, 0, stream>>>(Wq, 2048, W1T, 2048);
  wtrans<<<dim3(32, 8), 256, 0, stream>>>(Wk, 512, W1T + 2048 * 2048, 2048);
  wtrans<<<dim3(32, 8), 256, 0, stream>>>(Wv, 512, W1T + 2560 * 2048, 2048);
  // 2. fused QKV GEMM -> qkv bf16 (4096 x 3072)
  gemm_bt<1><<<dim3(24, 32), 256, 0, stream>>>(xb, W1T, qkv, 4096, 3072, 2048);
  // 3. RoPE + layout shuffles
  rope_q_kernel<<<16384, 256, 0, stream>>>(qkv, Qr);
  rope_k_kernel<<<4096, 256, 0, stream>>>(qkv, Kr, nsq);
  vtrans<<<dim3(16, 32), 256, 0, stream>>>(qkv, VT);
  wtrans<<<dim3(32, 32), 256, 0, stream>>>(Wo, 2048, WoT, 2048);
  // 4. flash attention -> y bf16 (b,t,H,64)
  attn_kernel<<<dim3(16, 32, 4), 256, 0, stream>>>(Qr, Kr, VT, nsq, y);
  // 5. output projection -> d_out fp32
  gemm_bt<0><<<dim3(16, 32), 256, 0, stream>>>(y, WoT, out, 4096, 2048, 2048);
}

// Round 2
// 373.721 us; speedup vs baseline: 1.4079x; 1.4079x over previous
//
#include <hip/hip_runtime.h>

typedef __bf16 bf16x8 __attribute__((ext_vector_type(8)));
typedef __bf16 bf16x4v __attribute__((ext_vector_type(4)));
typedef float f32x4 __attribute__((ext_vector_type(4)));

#define LDS_ASYNC16(g, l)                                            \
  __builtin_amdgcn_global_load_lds(                                  \
      (__attribute__((address_space(1))) void*)(g),                  \
      (__attribute__((address_space(3))) void*)(l), 16, 0, 0)

#define MFMA16(a, b, c) __builtin_amdgcn_mfma_f32_16x16x32_bf16(a, b, c, 0, 0, 0)

// ---------------------------------------------------------------------------
// cast fp32 -> bf16, 4 elems/thread
__global__ void cast_bf16(const float* __restrict__ x, __bf16* __restrict__ y,
                          int n4) {
  int i = blockIdx.x * 256 + threadIdx.x;
  if (i < n4) {
    float4 v = ((const float4*)x)[i];
    bf16x4v o;
    o[0] = (__bf16)v.x; o[1] = (__bf16)v.y; o[2] = (__bf16)v.z; o[3] = (__bf16)v.w;
    ((bf16x4v*)y)[i] = o;
  }
}

// ---------------------------------------------------------------------------
// transpose+cast: src (K x N) fp32 row-major -> dst (N x K) bf16 row-major
__global__ void wtrans(const float* __restrict__ src, int srcld,
                       __bf16* __restrict__ dst, int dstld) {
  __shared__ float tile[64][65];
  int k0 = blockIdx.x * 64, n0 = blockIdx.y * 64;
  int tl = threadIdx.x >> 6, c = threadIdx.x & 63;
#pragma unroll
  for (int rr = 0; rr < 16; ++rr) {
    int k = rr * 4 + tl;
    tile[k][c] = src[(size_t)(k0 + k) * srcld + n0 + c];
  }
  __syncthreads();
#pragma unroll
  for (int rr = 0; rr < 16; ++rr) {
    int n = rr * 4 + tl;
    dst[(size_t)(n0 + n) * dstld + k0 + c] = (__bf16)tile[c][n];
  }
}

// ---------------------------------------------------------------------------
// m97-style bf16 GEMM: C(MxN) = A(MxK) * B^T where B is (N x K) row-major.
template <int OUTBF16>
__global__ __launch_bounds__(256) void gemm_bt(const __bf16* __restrict__ A,
                                               const __bf16* __restrict__ B,
                                               void* __restrict__ Cout, int M,
                                               int N, int K) {
  __shared__ __bf16 As[128 * 32];
  __shared__ __bf16 Bs[128 * 32];
  int tid = threadIdx.x;
  int wave = tid >> 6, lane = tid & 63;
  int quad = lane >> 4, l16 = lane & 15;
  int wm = (wave & 1) * 64, wn = (wave >> 1) * 64;
  int tm = blockIdx.y * 128, tn = blockIdx.x * 128;

  f32x4 acc[4][4] = {};

  int srow = tid >> 2;
  int scol = (tid & 3) * 8;
  const __bf16* gA = A + (size_t)(tm + srow) * K + scol;
  const __bf16* gB = B + (size_t)(tn + srow) * K + scol;
  __bf16* lA0 = As + wave * 512;
  __bf16* lA1 = As + 2048 + wave * 512;
  __bf16* lB0 = Bs + wave * 512;
  __bf16* lB1 = Bs + 2048 + wave * 512;
  size_t stepA = (size_t)64 * K;

  for (int k0 = 0; k0 < K; k0 += 32) {
    LDS_ASYNC16(gA, lA0);
    LDS_ASYNC16(gA + stepA, lA1);
    LDS_ASYNC16(gB, lB0);
    LDS_ASYNC16(gB + stepA, lB1);
    gA += 32;
    gB += 32;
    __syncthreads();
    bf16x8 af[4], bfr[4];
#pragma unroll
    for (int mt = 0; mt < 4; ++mt)
      af[mt] = *(const bf16x8*)(As + (wm + mt * 16 + l16) * 32 + quad * 8);
#pragma unroll
    for (int nt = 0; nt < 4; ++nt)
      bfr[nt] = *(const bf16x8*)(Bs + (wn + nt * 16 + l16) * 32 + quad * 8);
#pragma unroll
    for (int mt = 0; mt < 4; ++mt)
#pragma unroll
      for (int nt = 0; nt < 4; ++nt)
        acc[mt][nt] = MFMA16(af[mt], bfr[nt], acc[mt][nt]);
    __syncthreads();
  }
  int r0 = tm + wm + quad * 4;
  int c0 = tn + wn + l16;
#pragma unroll
  for (int mt = 0; mt < 4; ++mt)
#pragma unroll
    for (int nt = 0; nt < 4; ++nt)
#pragma unroll
      for (int r = 0; r < 4; ++r) {
        size_t idx = (size_t)(r0 + mt * 16 + r) * N + (c0 + nt * 16);
        if (OUTBF16)
          ((__bf16*)Cout)[idx] = (__bf16)acc[mt][nt][r];
        else
          ((float*)Cout)[idx] = acc[mt][nt][r];
      }
}

// ---------------------------------------------------------------------------
// RoPE on Q, pre-scaled by 1/8 (exact pow2 in bf16): Qr (b,H,t,64)
__global__ void rope_q_kernel(const __bf16* __restrict__ qkv,
                              __bf16* __restrict__ Qr) {
  int n = blockIdx.x * 256 + threadIdx.x;
  int i = n & 31, h = (n >> 5) & 31, t = (n >> 10) & 1023, b = n >> 20;
  const __bf16* src = qkv + (size_t)(b * 1024 + t) * 3072 + h * 64;
  float x1 = (float)src[i], x2 = (float)src[i + 32];
  float ang = (float)t * expf((float)i * -0.28782313662425572f);
  float cv = cosf(ang), sv = sinf(ang);
  float o1 = (x1 * cv - x2 * sv) * 0.125f;
  float o2 = (x2 * cv + x1 * sv) * 0.125f;
  __bf16* dst = Qr + (((size_t)b * 32 + h) * 1024 + t) * 64;
  dst[i] = (__bf16)o1;
  dst[i + 32] = (__bf16)o2;
}

// RoPE on K + bias2 = -|k|^2/16 (score bias in the q/8-scaled domain)
__global__ void rope_k_kernel(const __bf16* __restrict__ qkv,
                              __bf16* __restrict__ Kr,
                              float* __restrict__ bias2) {
  int n = blockIdx.x * 256 + threadIdx.x;
  int i = n & 31, kvh = (n >> 5) & 7, t = (n >> 8) & 1023, b = n >> 18;
  const __bf16* src = qkv + (size_t)(b * 1024 + t) * 3072 + 2048 + kvh * 64;
  float x1 = (float)src[i], x2 = (float)src[i + 32];
  float ang = (float)t * expf((float)i * -0.28782313662425572f);
  float cv = cosf(ang), sv = sinf(ang);
  float o1 = x1 * cv - x2 * sv;
  float o2 = x2 * cv + x1 * sv;
  __bf16 b1 = (__bf16)o1, b2 = (__bf16)o2;
  float f1 = (float)b1, f2 = (float)b2;
  float nrm = f1 * f1 + f2 * f2;
#pragma unroll
  for (int off = 1; off < 32; off <<= 1) nrm += __shfl_xor(nrm, off, 64);
  __bf16* dst = Kr + (((size_t)b * 8 + kvh) * 1024 + t) * 64;
  dst[i] = b1;
  dst[i + 32] = b2;
  if (i == 0) bias2[((size_t)b * 8 + kvh) * 1024 + t] = -0.0625f * nrm;
}

// ---------------------------------------------------------------------------
// V transpose: qkv cols [2560,3072) -> VT (b,KV,64,t) bf16
__global__ void vtrans(const __bf16* __restrict__ qkv,
                       __bf16* __restrict__ VT) {
  __shared__ __bf16 tile[64][65];
  int tt = blockIdx.x, bkv = blockIdx.y;
  int b = bkv >> 3, kv = bkv & 7;
  int tl = threadIdx.x >> 6, d = threadIdx.x & 63;
#pragma unroll
  for (int rr = 0; rr < 16; ++rr) {
    int t_local = rr * 4 + tl;
    tile[t_local][d] =
        qkv[(size_t)(b * 1024 + tt * 64 + t_local) * 3072 + 2560 + kv * 64 + d];
  }
  __syncthreads();
#pragma unroll
  for (int rr = 0; rr < 16; ++rr) {
    int d_out = rr * 4 + tl;
    VT[((size_t)(b * 8 + kv) * 64 + d_out) * 1024 + tt * 64 + d] =
        tile[d][d_out];
  }
}

// ---------------------------------------------------------------------------
// Flash attention, conformal scores, S^T formulation.
// Block: 4 waves x 32 q-rows = 128 q-rows; K-tiles of 128 keys staged in LDS.
// S^T = K . Q^T  => C-layout: lane col = q (l16), rows = keys (quad*4+r+16mt)
// => per-lane softmax state; P round-trips LDS chunk-major into A-layout.
// grid: (8 qtiles, 32 heads, 4 batch), 256 threads.
__global__ __launch_bounds__(256, 2) void attn_kernel(
    const __bf16* __restrict__ Q, const __bf16* __restrict__ Kc,
    const __bf16* __restrict__ VT, const float* __restrict__ bias2,
    __bf16* __restrict__ Y) {
  const int T = 1024;
  int qt = blockIdx.x, h = blockIdx.y, b = blockIdx.z;
  int kv = h >> 2;
  int tid = threadIdx.x;
  int wave = tid >> 6, lane = tid & 63;
  int quad = lane >> 4, l16 = lane & 15;

  // chunk-major LDS: [16B-chunk][row] so b128 reads spread banks evenly
  __shared__ __bf16 Ks[8 * 128 * 8];    // [c: d-chunk 0..7][key 0..127][8]
  __shared__ __bf16 Vs[16 * 64 * 8];    // [c: key-chunk 0..15][d 0..63][8]
  __shared__ __bf16 Ps[4][16 * 32 * 8]; // per wave [cp][qslot][8]
  __shared__ float Al[4][32];           // per wave alpha/linv broadcast

  const __bf16* Qb = Q + (((size_t)b * 32 + h) * T + qt * 128 + wave * 32) * 64;
  const __bf16* Kb = Kc + ((size_t)b * 8 + kv) * T * 64;
  const __bf16* Vb = VT + ((size_t)b * 8 + kv) * 64 * T;
  const float* nb = bias2 + ((size_t)b * 8 + kv) * T;
  __bf16* Pw = &Ps[wave][0];

  // Q B-frags (lane: n=q=l16(+16nt), k=d=kd*32+quad*8+j), held all kernel
  bf16x8 qf[2][2];
#pragma unroll
  for (int nt = 0; nt < 2; ++nt)
#pragma unroll
    for (int kd = 0; kd < 2; ++kd)
      qf[nt][kd] =
          *(const bf16x8*)(Qb + (size_t)(nt * 16 + l16) * 64 + kd * 32 + quad * 8);

  f32x4 oacc[2][4] = {};
  float m_i[2] = {-1e30f, -1e30f};
  float lsum[2] = {0.f, 0.f};

  for (int j = 0; j <= qt; ++j) {
    int k0 = j * 128;
    bool diag = (j == qt);
    __syncthreads();  // prev-tile LDS reads done before restage
    // ---- stage K (waves 0,1) and V (waves 2,3), 8 x 1KB each
#pragma unroll
    for (int u = 0; u < 8; ++u) {
      int t = wave * 8 + u;
      if (t < 16) {
        int c = t >> 1, kh = t & 1;
        LDS_ASYNC16(Kb + (size_t)(k0 + kh * 64) * 64 + c * 8 + (size_t)lane * 64,
                    Ks + c * 1024 + kh * 512);
      } else {
        int c = t - 16;
        LDS_ASYNC16(Vb + (size_t)lane * T + k0 + c * 8, Vs + c * 512);
      }
    }
    __syncthreads();  // drain vmcnt: K/V visible

    // ---- S^T = K . Q^T : sacc[mt][nt], rows=keys cols=q
    f32x4 sacc[8][2];
#pragma unroll
    for (int mt = 0; mt < 8; ++mt) {
      sacc[mt][0] = (f32x4){0.f, 0.f, 0.f, 0.f};
      sacc[mt][1] = (f32x4){0.f, 0.f, 0.f, 0.f};
    }
#pragma unroll
    for (int kd = 0; kd < 2; ++kd)
#pragma unroll
      for (int mt = 0; mt < 8; ++mt) {
        bf16x8 kf =
            *(const bf16x8*)(Ks + (kd * 4 + quad) * 1024 + (mt * 16 + l16) * 8);
        sacc[mt][0] = MFMA16(kf, qf[0][kd], sacc[mt][0]);
        sacc[mt][1] = MFMA16(kf, qf[1][kd], sacc[mt][1]);
      }

    // ---- bias + causal mask (diag tile only)
#pragma unroll
    for (int mt = 0; mt < 8; ++mt) {
      f32x4 bv = *(const f32x4*)(nb + k0 + mt * 16 + quad * 4);
#pragma unroll
      for (int nt = 0; nt < 2; ++nt)
#pragma unroll
        for (int r = 0; r < 4; ++r) {
          float xv = sacc[mt][nt][r] + bv[r];
          if (diag) {
            int key = mt * 16 + quad * 4 + r;
            int ql = wave * 32 + nt * 16 + l16;
            xv = (key <= ql) ? xv : -1e30f;
          }
          sacc[mt][nt][r] = xv;
        }
    }

    // ---- online max (local + 2 shfl across quads)
    float mx0 = -1e30f, mx1 = -1e30f;
#pragma unroll
    for (int mt = 0; mt < 8; ++mt)
#pragma unroll
      for (int r = 0; r < 4; ++r) {
        mx0 = fmaxf(mx0, sacc[mt][0][r]);
        mx1 = fmaxf(mx1, sacc[mt][1][r]);
      }
    mx0 = fmaxf(mx0, __shfl_xor(mx0, 16));
    mx0 = fmaxf(mx0, __shfl_xor(mx0, 32));
    mx1 = fmaxf(mx1, __shfl_xor(mx1, 16));
    mx1 = fmaxf(mx1, __shfl_xor(mx1, 32));
    float mn0 = fmaxf(m_i[0], mx0), mn1 = fmaxf(m_i[1], mx1);
    float a0 = __expf(m_i[0] - mn0), a1 = __expf(m_i[1] - mn1);
    m_i[0] = mn0;
    m_i[1] = mn1;

    // ---- P = exp(x-m): pack bf16x4, write chunk-major w/ +2cp rotation
    float ls0 = 0.f, ls1 = 0.f;
#pragma unroll
    for (int mt = 0; mt < 8; ++mt) {
      int cp = 2 * mt + (quad >> 1);
      int halfo = (quad & 1) * 4;
#pragma unroll
      for (int nt = 0; nt < 2; ++nt) {
        float mm = nt ? mn1 : mn0;
        bf16x4v pk;
        float lacc = 0.f;
#pragma unroll
        for (int r = 0; r < 4; ++r) {
          float p = __expf(sacc[mt][nt][r] - mm);
          lacc += p;
          pk[r] = (__bf16)p;
        }
        if (nt)
          ls1 += lacc;
        else
          ls0 += lacc;
        int qs = ((nt * 16 + l16) + 2 * cp) & 31;
        *(bf16x4v*)(Pw + cp * 256 + qs * 8 + halfo) = pk;
      }
    }
    lsum[0] = lsum[0] * a0 + ls0;
    lsum[1] = lsum[1] * a1 + ls1;

    // ---- rescale O by alpha (per-q broadcast via wave-private LDS)
    if (quad == 0) {
      Al[wave][l16] = a0;
      Al[wave][16 + l16] = a1;
    }
    f32x4 av0 = *(const f32x4*)(&Al[wave][quad * 4]);
    f32x4 av1 = *(const f32x4*)(&Al[wave][16 + quad * 4]);
#pragma unroll
    for (int dt = 0; dt < 4; ++dt)
#pragma unroll
      for (int r = 0; r < 4; ++r) {
        oacc[0][dt][r] *= av0[r];
        oacc[1][dt][r] *= av1[r];
      }

    // ---- O += P V (P A-frags from LDS, V B-frags from LDS)
#pragma unroll
    for (int ki = 0; ki < 4; ++ki) {
      int cp = 4 * ki + quad;
      bf16x8 pf0 = *(const bf16x8*)(Pw + cp * 256 + ((l16 + 2 * cp) & 31) * 8);
      bf16x8 pf1 =
          *(const bf16x8*)(Pw + cp * 256 + ((16 + l16 + 2 * cp) & 31) * 8);
#pragma unroll
      for (int dt = 0; dt < 4; ++dt) {
        bf16x8 vf = *(const bf16x8*)(Vs + cp * 512 + (dt * 16 + l16) * 8);
        oacc[0][dt] = MFMA16(pf0, vf, oacc[0][dt]);
        oacc[1][dt] = MFMA16(pf1, vf, oacc[1][dt]);
      }
    }
  }

  // ---- epilogue: finish l across quads, divide, store Y (b,t,H,64)
  lsum[0] += __shfl_xor(lsum[0], 16);
  lsum[0] += __shfl_xor(lsum[0], 32);
  lsum[1] += __shfl_xor(lsum[1], 16);
  lsum[1] += __shfl_xor(lsum[1], 32);
  if (quad == 0) {
    Al[wave][l16] = 1.f / lsum[0];
    Al[wave][16 + l16] = 1.f / lsum[1];
  }
  f32x4 lv0 = *(const f32x4*)(&Al[wave][quad * 4]);
  f32x4 lv1 = *(const f32x4*)(&Al[wave][16 + quad * 4]);
  __bf16* Yb = Y + (((size_t)b * T + qt * 128 + wave * 32) * 32 + h) * 64;
#pragma unroll
  for (int nt = 0; nt < 2; ++nt)
#pragma unroll
    for (int dt = 0; dt < 4; ++dt)
#pragma unroll
      for (int r = 0; r < 4; ++r) {
        float lv = nt ? lv1[r] : lv0[r];
        Yb[(size_t)(nt * 16 + quad * 4 + r) * 2048 + dt * 16 + l16] =
            (__bf16)(oacc[nt][dt][r] * lv);
      }
}

// ---------------------------------------------------------------------------
extern "C" void kernel_launch(void* const* d_in, const int* in_sizes, int n_in,
                              void* d_out, int out_size, void* d_ws,
                              size_t ws_size, hipStream_t stream) {
  const float* x = (const float*)d_in[0];
  const float* Wq = (const float*)d_in[1];
  const float* Wk = (const float*)d_in[2];
  const float* Wv = (const float*)d_in[3];
  const float* Wo = (const float*)d_in[4];
  float* out = (float*)d_out;

  char* ws = (char*)d_ws;
  __bf16* xb = (__bf16*)(ws);                            // 16.8MB, reused as Qr
  __bf16* W1T = (__bf16*)(ws + 16777216);                // 12.6MB, reused as WoT
  __bf16* qkv = (__bf16*)(ws + 16777216 + 12582912);     // 25.2MB, reused as y
  char* d4 = ws + 16777216 + 12582912 + 25165824;
  __bf16* Kr = (__bf16*)(d4);
  __bf16* VT = (__bf16*)(d4 + 4194304);
  float* bias2 = (float*)(d4 + 8388608);
  __bf16* Qr = xb;
  __bf16* WoT = W1T;
  __bf16* y = qkv;

  cast_bf16<<<8192, 256, 0, stream>>>(x, xb, 2097152);
  wtrans<<<dim3(32, 32), 256, 0, stream>>>(Wq, 2048, W1T, 2048);
  wtrans<<<dim3(32, 8), 256, 0, stream>>>(Wk, 512, W1T + 2048 * 2048, 2048);
  wtrans<<<dim3(32, 8), 256, 0, stream>>>(Wv, 512, W1T + 2560 * 2048, 2048);
  gemm_bt<1><<<dim3(24, 32), 256, 0, stream>>>(xb, W1T, qkv, 4096, 3072, 2048);
  rope_q_kernel<<<16384, 256, 0, stream>>>(qkv, Qr);
  rope_k_kernel<<<4096, 256, 0, stream>>>(qkv, Kr, bias2);
  vtrans<<<dim3(16, 32), 256, 0, stream>>>(qkv, VT);
  wtrans<<<dim3(32, 32), 256, 0, stream>>>(Wo, 2048, WoT, 2048);
  attn_kernel<<<dim3(8, 32, 4), 256, 0, stream>>>(Qr, Kr, VT, bias2, y);
  gemm_bt<0><<<dim3(16, 32), 256, 0, stream>>>(y, WoT, out, 4096, 2048, 2048);
}

// Round 3
// 358.755 us; speedup vs baseline: 1.4667x; 1.0417x over previous
//
#include <hip/hip_runtime.h>

typedef __bf16 bf16x8 __attribute__((ext_vector_type(8)));
typedef __bf16 bf16x4v __attribute__((ext_vector_type(4)));
typedef float f32x4 __attribute__((ext_vector_type(4)));

#define LDS_ASYNC16(g, l)                                            \
  __builtin_amdgcn_global_load_lds(                                  \
      (__attribute__((address_space(1))) void*)(g),                  \
      (__attribute__((address_space(3))) void*)(l), 16, 0, 0)

#define MFMA16(a, b, c) __builtin_amdgcn_mfma_f32_16x16x32_bf16(a, b, c, 0, 0, 0)

#if __has_builtin(__builtin_amdgcn_exp2f)
#define EXP2F(x) __builtin_amdgcn_exp2f(x)
#else
#define EXP2F(x) exp2f(x)
#endif

// log2(e)/8 and -log2(e)/16: scores computed directly in log2 domain.
#define QSCALE 0.18033688011112042f
#define KBIAS -0.09016844005556021f

// ---------------------------------------------------------------------------
// cast fp32 -> bf16, 4 elems/thread
__global__ void cast_bf16(const float* __restrict__ x, __bf16* __restrict__ y,
                          int n4) {
  int i = blockIdx.x * 256 + threadIdx.x;
  if (i < n4) {
    float4 v = ((const float4*)x)[i];
    bf16x4v o;
    o[0] = (__bf16)v.x; o[1] = (__bf16)v.y; o[2] = (__bf16)v.z; o[3] = (__bf16)v.w;
    ((bf16x4v*)y)[i] = o;
  }
}

// ---------------------------------------------------------------------------
// transpose+cast: src (K x N) fp32 row-major -> dst (N x K) bf16 row-major
__global__ void wtrans(const float* __restrict__ src, int srcld,
                       __bf16* __restrict__ dst, int dstld) {
  __shared__ float tile[64][65];
  int k0 = blockIdx.x * 64, n0 = blockIdx.y * 64;
  int tl = threadIdx.x >> 6, c = threadIdx.x & 63;
#pragma unroll
  for (int rr = 0; rr < 16; ++rr) {
    int k = rr * 4 + tl;
    tile[k][c] = src[(size_t)(k0 + k) * srcld + n0 + c];
  }
  __syncthreads();
#pragma unroll
  for (int rr = 0; rr < 16; ++rr) {
    int n = rr * 4 + tl;
    dst[(size_t)(n0 + n) * dstld + k0 + c] = (__bf16)tile[c][n];
  }
}

// ---------------------------------------------------------------------------
// m97-style bf16 GEMM: C(MxN) = A(MxK) * B^T where B is (N x K) row-major.
template <int OUTBF16>
__global__ __launch_bounds__(256) void gemm_bt(const __bf16* __restrict__ A,
                                               const __bf16* __restrict__ B,
                                               void* __restrict__ Cout, int M,
                                               int N, int K) {
  __shared__ __bf16 As[128 * 32];
  __shared__ __bf16 Bs[128 * 32];
  int tid = threadIdx.x;
  int wave = tid >> 6, lane = tid & 63;
  int quad = lane >> 4, l16 = lane & 15;
  int wm = (wave & 1) * 64, wn = (wave >> 1) * 64;
  int tm = blockIdx.y * 128, tn = blockIdx.x * 128;

  f32x4 acc[4][4] = {};

  int srow = tid >> 2;
  int scol = (tid & 3) * 8;
  const __bf16* gA = A + (size_t)(tm + srow) * K + scol;
  const __bf16* gB = B + (size_t)(tn + srow) * K + scol;
  __bf16* lA0 = As + wave * 512;
  __bf16* lA1 = As + 2048 + wave * 512;
  __bf16* lB0 = Bs + wave * 512;
  __bf16* lB1 = Bs + 2048 + wave * 512;
  size_t stepA = (size_t)64 * K;

  for (int k0 = 0; k0 < K; k0 += 32) {
    LDS_ASYNC16(gA, lA0);
    LDS_ASYNC16(gA + stepA, lA1);
    LDS_ASYNC16(gB, lB0);
    LDS_ASYNC16(gB + stepA, lB1);
    gA += 32;
    gB += 32;
    __syncthreads();
    bf16x8 af[4], bfr[4];
#pragma unroll
    for (int mt = 0; mt < 4; ++mt)
      af[mt] = *(const bf16x8*)(As + (wm + mt * 16 + l16) * 32 + quad * 8);
#pragma unroll
    for (int nt = 0; nt < 4; ++nt)
      bfr[nt] = *(const bf16x8*)(Bs + (wn + nt * 16 + l16) * 32 + quad * 8);
#pragma unroll
    for (int mt = 0; mt < 4; ++mt)
#pragma unroll
      for (int nt = 0; nt < 4; ++nt)
        acc[mt][nt] = MFMA16(af[mt], bfr[nt], acc[mt][nt]);
    __syncthreads();
  }
  int r0 = tm + wm + quad * 4;
  int c0 = tn + wn + l16;
#pragma unroll
  for (int mt = 0; mt < 4; ++mt)
#pragma unroll
    for (int nt = 0; nt < 4; ++nt)
#pragma unroll
      for (int r = 0; r < 4; ++r) {
        size_t idx = (size_t)(r0 + mt * 16 + r) * N + (c0 + nt * 16);
        if (OUTBF16)
          ((__bf16*)Cout)[idx] = (__bf16)acc[mt][nt][r];
        else
          ((float*)Cout)[idx] = acc[mt][nt][r];
      }
}

// ---------------------------------------------------------------------------
// RoPE on Q, pre-scaled by log2(e)/8: Qr (b,H,t,64)
__global__ void rope_q_kernel(const __bf16* __restrict__ qkv,
                              __bf16* __restrict__ Qr) {
  int n = blockIdx.x * 256 + threadIdx.x;
  int i = n & 31, h = (n >> 5) & 31, t = (n >> 10) & 1023, b = n >> 20;
  const __bf16* src = qkv + (size_t)(b * 1024 + t) * 3072 + h * 64;
  float x1 = (float)src[i], x2 = (float)src[i + 32];
  float ang = (float)t * expf((float)i * -0.28782313662425572f);
  float cv = cosf(ang), sv = sinf(ang);
  float o1 = (x1 * cv - x2 * sv) * QSCALE;
  float o2 = (x2 * cv + x1 * sv) * QSCALE;
  __bf16* dst = Qr + (((size_t)b * 32 + h) * 1024 + t) * 64;
  dst[i] = (__bf16)o1;
  dst[i + 32] = (__bf16)o2;
}

// RoPE on K + bias2 = -log2(e)*|k|^2/16 (log2-domain conformal bias)
__global__ void rope_k_kernel(const __bf16* __restrict__ qkv,
                              __bf16* __restrict__ Kr,
                              float* __restrict__ bias2) {
  int n = blockIdx.x * 256 + threadIdx.x;
  int i = n & 31, kvh = (n >> 5) & 7, t = (n >> 8) & 1023, b = n >> 18;
  const __bf16* src = qkv + (size_t)(b * 1024 + t) * 3072 + 2048 + kvh * 64;
  float x1 = (float)src[i], x2 = (float)src[i + 32];
  float ang = (float)t * expf((float)i * -0.28782313662425572f);
  float cv = cosf(ang), sv = sinf(ang);
  float o1 = x1 * cv - x2 * sv;
  float o2 = x2 * cv + x1 * sv;
  __bf16 b1 = (__bf16)o1, b2 = (__bf16)o2;
  float f1 = (float)b1, f2 = (float)b2;
  float nrm = f1 * f1 + f2 * f2;
#pragma unroll
  for (int off = 1; off < 32; off <<= 1) nrm += __shfl_xor(nrm, off, 64);
  __bf16* dst = Kr + (((size_t)b * 8 + kvh) * 1024 + t) * 64;
  dst[i] = b1;
  dst[i + 32] = b2;
  if (i == 0) bias2[((size_t)b * 8 + kvh) * 1024 + t] = KBIAS * nrm;
}

// ---------------------------------------------------------------------------
// V transpose: qkv cols [2560,3072) -> VT (b,KV,64,t) bf16
__global__ void vtrans(const __bf16* __restrict__ qkv,
                       __bf16* __restrict__ VT) {
  __shared__ __bf16 tile[64][65];
  int tt = blockIdx.x, bkv = blockIdx.y;
  int b = bkv >> 3, kv = bkv & 7;
  int tl = threadIdx.x >> 6, d = threadIdx.x & 63;
#pragma unroll
  for (int rr = 0; rr < 16; ++rr) {
    int t_local = rr * 4 + tl;
    tile[t_local][d] =
        qkv[(size_t)(b * 1024 + tt * 64 + t_local) * 3072 + 2560 + kv * 64 + d];
  }
  __syncthreads();
#pragma unroll
  for (int rr = 0; rr < 16; ++rr) {
    int d_out = rr * 4 + tl;
    VT[((size_t)(b * 8 + kv) * 64 + d_out) * 1024 + tt * 64 + d] =
        tile[d][d_out];
  }
}

// ---------------------------------------------------------------------------
// Flash attention, conformal scores, S^T formulation, NO online max:
// full conformal score <= 0 (s = -|q-k|^2/(2 sqrt(d))), so with only the
// per-row q-term dropped, p = 2^s is bounded by 2^(|q|^2 log2e/16) ~ 1e3 and
// l <= 1e6: f32-safe without max subtraction. Row sums l accumulate via an
// extra ones-B MFMA (same lane mapping as oacc -> shuffle-free epilogue).
// grid: (32 heads, 8 qtiles reversed, 4 batch), 256 threads.
__global__ __launch_bounds__(256, 3) void attn_kernel(
    const __bf16* __restrict__ Q, const __bf16* __restrict__ Kc,
    const __bf16* __restrict__ VT, const float* __restrict__ bias2,
    __bf16* __restrict__ Y) {
  const int T = 1024;
  int h = blockIdx.x, qt = 7 - blockIdx.y, b = blockIdx.z;
  int kv = h >> 2;
  int tid = threadIdx.x;
  int wave = tid >> 6, lane = tid & 63;
  int quad = lane >> 4, l16 = lane & 15;

  __shared__ __bf16 Ks[8 * 128 * 8];    // 16KB [d-chunk][key][8]
  __shared__ __bf16 Vs[16 * 64 * 8];    // 16KB [key-chunk][d][8]
  __shared__ __bf16 Ps[4][8 * 32 * 8];  // 16KB: 4KB/wave [cp][qslot][8]

  const __bf16* Qb = Q + (((size_t)b * 32 + h) * T + qt * 128 + wave * 32) * 64;
  const __bf16* Kb = Kc + ((size_t)b * 8 + kv) * T * 64;
  const __bf16* Vb = VT + ((size_t)b * 8 + kv) * 64 * T;
  const float* nb = bias2 + ((size_t)b * 8 + kv) * T;
  __bf16* Pw = &Ps[wave][0];

  // Q B-frags (n=q=l16(+16nt), k=d=kd*32+quad*8+j), held all kernel
  bf16x8 qf[2][2];
#pragma unroll
  for (int nt = 0; nt < 2; ++nt)
#pragma unroll
    for (int kd = 0; kd < 2; ++kd)
      qf[nt][kd] =
          *(const bf16x8*)(Qb + (size_t)(nt * 16 + l16) * 64 + kd * 32 + quad * 8);

  bf16x8 onesf;
#pragma unroll
  for (int u = 0; u < 8; ++u) onesf[u] = (__bf16)1.0f;

  f32x4 oacc[2][4] = {};
  f32x4 lacc[2] = {};

  for (int j = 0; j <= qt; ++j) {
    int k0 = j * 128;
    bool diag = (j == qt);
    __syncthreads();  // prev-tile LDS reads done before restage
#pragma unroll
    for (int u = 0; u < 8; ++u) {
      int t = wave * 8 + u;
      if (t < 16) {
        int c = t >> 1, kh = t & 1;
        LDS_ASYNC16(Kb + (size_t)(k0 + kh * 64) * 64 + c * 8 + (size_t)lane * 64,
                    Ks + c * 1024 + kh * 512);
      } else {
        int c = t - 16;
        LDS_ASYNC16(Vb + (size_t)lane * T + k0 + c * 8, Vs + c * 512);
      }
    }
    __syncthreads();  // drain vmcnt: K/V visible

    // ---- S^T = K.Q^T, acc initialized to the per-key bias
    f32x4 sacc[8][2];
#pragma unroll
    for (int mt = 0; mt < 8; ++mt) {
      f32x4 bv = *(const f32x4*)(nb + k0 + mt * 16 + quad * 4);
      sacc[mt][0] = bv;
      sacc[mt][1] = bv;
    }
#pragma unroll
    for (int kd = 0; kd < 2; ++kd)
#pragma unroll
      for (int mt = 0; mt < 8; ++mt) {
        bf16x8 kf =
            *(const bf16x8*)(Ks + (kd * 4 + quad) * 1024 + (mt * 16 + l16) * 8);
        sacc[mt][0] = MFMA16(kf, qf[0][kd], sacc[mt][0]);
        sacc[mt][1] = MFMA16(kf, qf[1][kd], sacc[mt][1]);
      }

    if (diag) {  // causal mask, diagonal tile only
#pragma unroll
      for (int mt = 0; mt < 8; ++mt)
#pragma unroll
        for (int nt = 0; nt < 2; ++nt)
#pragma unroll
          for (int r = 0; r < 4; ++r) {
            int key = mt * 16 + quad * 4 + r;
            int ql = wave * 32 + nt * 16 + l16;
            if (key > ql) sacc[mt][nt][r] = -1e30f;
          }
    }

    // ---- two 64-key halves: exp2 -> Ps -> PV + ones-MFMA
#pragma unroll
    for (int kh = 0; kh < 2; ++kh) {
#pragma unroll
      for (int mh = 0; mh < 4; ++mh) {
        int mt = 4 * kh + mh;
        int cp = 2 * mh + (quad >> 1);
        int halfo = (quad & 1) * 4;
#pragma unroll
        for (int nt = 0; nt < 2; ++nt) {
          bf16x4v pk;
#pragma unroll
          for (int r = 0; r < 4; ++r) pk[r] = (__bf16)EXP2F(sacc[mt][nt][r]);
          int qs = ((nt * 16 + l16) + 2 * cp) & 31;
          *(bf16x4v*)(Pw + cp * 256 + qs * 8 + halfo) = pk;
        }
      }
#pragma unroll
      for (int kil = 0; kil < 2; ++kil) {
        int cp = 4 * kil + quad;
        bf16x8 pf0 = *(const bf16x8*)(Pw + cp * 256 + ((l16 + 2 * cp) & 31) * 8);
        bf16x8 pf1 =
            *(const bf16x8*)(Pw + cp * 256 + ((16 + l16 + 2 * cp) & 31) * 8);
        lacc[0] = MFMA16(pf0, onesf, lacc[0]);
        lacc[1] = MFMA16(pf1, onesf, lacc[1]);
        int ckv = 8 * kh + cp;
#pragma unroll
        for (int dt = 0; dt < 4; ++dt) {
          bf16x8 vf = *(const bf16x8*)(Vs + ckv * 512 + (dt * 16 + l16) * 8);
          oacc[0][dt] = MFMA16(pf0, vf, oacc[0][dt]);
          oacc[1][dt] = MFMA16(pf1, vf, oacc[1][dt]);
        }
      }
    }
  }

  // ---- epilogue: per-lane l (same row mapping as oacc), store Y (b,t,H,64)
  __bf16* Yb = Y + (((size_t)b * T + qt * 128 + wave * 32) * 32 + h) * 64;
#pragma unroll
  for (int nt = 0; nt < 2; ++nt)
#pragma unroll
    for (int r = 0; r < 4; ++r) {
      float linv = 1.0f / lacc[nt][r];
#pragma unroll
      for (int dt = 0; dt < 4; ++dt)
        Yb[(size_t)(nt * 16 + quad * 4 + r) * 2048 + dt * 16 + l16] =
            (__bf16)(oacc[nt][dt][r] * linv);
    }
}

// ---------------------------------------------------------------------------
extern "C" void kernel_launch(void* const* d_in, const int* in_sizes, int n_in,
                              void* d_out, int out_size, void* d_ws,
                              size_t ws_size, hipStream_t stream) {
  const float* x = (const float*)d_in[0];
  const float* Wq = (const float*)d_in[1];
  const float* Wk = (const float*)d_in[2];
  const float* Wv = (const float*)d_in[3];
  const float* Wo = (const float*)d_in[4];
  float* out = (float*)d_out;

  char* ws = (char*)d_ws;
  __bf16* xb = (__bf16*)(ws);                            // 16.8MB, reused as Qr
  __bf16* W1T = (__bf16*)(ws + 16777216);                // 12.6MB, reused as WoT
  __bf16* qkv = (__bf16*)(ws + 16777216 + 12582912);     // 25.2MB, reused as y
  char* d4 = ws + 16777216 + 12582912 + 25165824;
  __bf16* Kr = (__bf16*)(d4);
  __bf16* VT = (__bf16*)(d4 + 4194304);
  float* bias2 = (float*)(d4 + 8388608);
  __bf16* Qr = xb;
  __bf16* WoT = W1T;
  __bf16* y = qkv;

  cast_bf16<<<8192, 256, 0, stream>>>(x, xb, 2097152);
  wtrans<<<dim3(32, 32), 256, 0, stream>>>(Wq, 2048, W1T, 2048);
  wtrans<<<dim3(32, 8), 256, 0, stream>>>(Wk, 512, W1T + 2048 * 2048, 2048);
  wtrans<<<dim3(32, 8), 256, 0, stream>>>(Wv, 512, W1T + 2560 * 2048, 2048);
  gemm_bt<1><<<dim3(24, 32), 256, 0, stream>>>(xb, W1T, qkv, 4096, 3072, 2048);
  rope_q_kernel<<<16384, 256, 0, stream>>>(qkv, Qr);
  rope_k_kernel<<<4096, 256, 0, stream>>>(qkv, Kr, bias2);
  vtrans<<<dim3(16, 32), 256, 0, stream>>>(qkv, VT);
  wtrans<<<dim3(32, 32), 256, 0, stream>>>(Wo, 2048, WoT, 2048);
  attn_kernel<<<dim3(32, 8, 4), 256, 0, stream>>>(Qr, Kr, VT, bias2, y);
  gemm_bt<0><<<dim3(16, 32), 256, 0, stream>>>(y, WoT, out, 4096, 2048, 2048);
}

// Round 4
// 317.243 us; speedup vs baseline: 1.6586x; 1.1309x over previous
//
#include <hip/hip_runtime.h>

typedef __bf16 bf16x8 __attribute__((ext_vector_type(8)));
typedef __bf16 bf16x4v __attribute__((ext_vector_type(4)));
typedef float f32x4 __attribute__((ext_vector_type(4)));

#define LDS_ASYNC16(g, l)                                            \
  __builtin_amdgcn_global_load_lds(                                  \
      (__attribute__((address_space(1))) void*)(g),                  \
      (__attribute__((address_space(3))) void*)(l), 16, 0, 0)

#define MFMA16(a, b, c) __builtin_amdgcn_mfma_f32_16x16x32_bf16(a, b, c, 0, 0, 0)

#if __has_builtin(__builtin_amdgcn_exp2f)
#define EXP2F(x) __builtin_amdgcn_exp2f(x)
#else
#define EXP2F(x) exp2f(x)
#endif

// log2(e)/8 and -log2(e)/16: scores computed directly in log2 domain.
#define QSCALE 0.18033688011112042f
#define KBIAS -0.09016844005556021f

// ---------------------------------------------------------------------------
// cast fp32 -> bf16, 4 elems/thread
__global__ void cast_bf16(const float* __restrict__ x, __bf16* __restrict__ y,
                          int n4) {
  int i = blockIdx.x * 256 + threadIdx.x;
  if (i < n4) {
    float4 v = ((const float4*)x)[i];
    bf16x4v o;
    o[0] = (__bf16)v.x; o[1] = (__bf16)v.y; o[2] = (__bf16)v.z; o[3] = (__bf16)v.w;
    ((bf16x4v*)y)[i] = o;
  }
}

// ---------------------------------------------------------------------------
// transpose+cast: src (K x N) fp32 row-major -> dst (N x K) bf16 row-major
__global__ void wtrans(const float* __restrict__ src, int srcld,
                       __bf16* __restrict__ dst, int dstld) {
  __shared__ float tile[64][65];
  int k0 = blockIdx.x * 64, n0 = blockIdx.y * 64;
  int tl = threadIdx.x >> 6, c = threadIdx.x & 63;
#pragma unroll
  for (int rr = 0; rr < 16; ++rr) {
    int k = rr * 4 + tl;
    tile[k][c] = src[(size_t)(k0 + k) * srcld + n0 + c];
  }
  __syncthreads();
#pragma unroll
  for (int rr = 0; rr < 16; ++rr) {
    int n = rr * 4 + tl;
    dst[(size_t)(n0 + n) * dstld + k0 + c] = (__bf16)tile[c][n];
  }
}

// ---------------------------------------------------------------------------
// m97-style bf16 GEMM: C(MxN) = A(MxK) * B^T where B is (N x K) row-major.
template <int OUTBF16>
__global__ __launch_bounds__(256) void gemm_bt(const __bf16* __restrict__ A,
                                               const __bf16* __restrict__ B,
                                               void* __restrict__ Cout, int M,
                                               int N, int K) {
  __shared__ __bf16 As[128 * 32];
  __shared__ __bf16 Bs[128 * 32];
  int tid = threadIdx.x;
  int wave = tid >> 6, lane = tid & 63;
  int quad = lane >> 4, l16 = lane & 15;
  int wm = (wave & 1) * 64, wn = (wave >> 1) * 64;
  int tm = blockIdx.y * 128, tn = blockIdx.x * 128;

  f32x4 acc[4][4] = {};

  int srow = tid >> 2;
  int scol = (tid & 3) * 8;
  const __bf16* gA = A + (size_t)(tm + srow) * K + scol;
  const __bf16* gB = B + (size_t)(tn + srow) * K + scol;
  __bf16* lA0 = As + wave * 512;
  __bf16* lA1 = As + 2048 + wave * 512;
  __bf16* lB0 = Bs + wave * 512;
  __bf16* lB1 = Bs + 2048 + wave * 512;
  size_t stepA = (size_t)64 * K;

  for (int k0 = 0; k0 < K; k0 += 32) {
    LDS_ASYNC16(gA, lA0);
    LDS_ASYNC16(gA + stepA, lA1);
    LDS_ASYNC16(gB, lB0);
    LDS_ASYNC16(gB + stepA, lB1);
    gA += 32;
    gB += 32;
    __syncthreads();
    bf16x8 af[4], bfr[4];
#pragma unroll
    for (int mt = 0; mt < 4; ++mt)
      af[mt] = *(const bf16x8*)(As + (wm + mt * 16 + l16) * 32 + quad * 8);
#pragma unroll
    for (int nt = 0; nt < 4; ++nt)
      bfr[nt] = *(const bf16x8*)(Bs + (wn + nt * 16 + l16) * 32 + quad * 8);
#pragma unroll
    for (int mt = 0; mt < 4; ++mt)
#pragma unroll
      for (int nt = 0; nt < 4; ++nt)
        acc[mt][nt] = MFMA16(af[mt], bfr[nt], acc[mt][nt]);
    __syncthreads();
  }
  int r0 = tm + wm + quad * 4;
  int c0 = tn + wn + l16;
#pragma unroll
  for (int mt = 0; mt < 4; ++mt)
#pragma unroll
    for (int nt = 0; nt < 4; ++nt)
#pragma unroll
      for (int r = 0; r < 4; ++r) {
        size_t idx = (size_t)(r0 + mt * 16 + r) * N + (c0 + nt * 16);
        if (OUTBF16)
          ((__bf16*)Cout)[idx] = (__bf16)acc[mt][nt][r];
        else
          ((float*)Cout)[idx] = acc[mt][nt][r];
      }
}

// ---------------------------------------------------------------------------
// RoPE on Q, pre-scaled by log2(e)/8: Qr (b,H,t,64)
__global__ void rope_q_kernel(const __bf16* __restrict__ qkv,
                              __bf16* __restrict__ Qr) {
  int n = blockIdx.x * 256 + threadIdx.x;
  int i = n & 31, h = (n >> 5) & 31, t = (n >> 10) & 1023, b = n >> 20;
  const __bf16* src = qkv + (size_t)(b * 1024 + t) * 3072 + h * 64;
  float x1 = (float)src[i], x2 = (float)src[i + 32];
  float ang = (float)t * expf((float)i * -0.28782313662425572f);
  float cv = cosf(ang), sv = sinf(ang);
  float o1 = (x1 * cv - x2 * sv) * QSCALE;
  float o2 = (x2 * cv + x1 * sv) * QSCALE;
  __bf16* dst = Qr + (((size_t)b * 32 + h) * 1024 + t) * 64;
  dst[i] = (__bf16)o1;
  dst[i + 32] = (__bf16)o2;
}

// RoPE on K + bias2 = -log2(e)*|k|^2/16 (log2-domain conformal bias)
__global__ void rope_k_kernel(const __bf16* __restrict__ qkv,
                              __bf16* __restrict__ Kr,
                              float* __restrict__ bias2) {
  int n = blockIdx.x * 256 + threadIdx.x;
  int i = n & 31, kvh = (n >> 5) & 7, t = (n >> 8) & 1023, b = n >> 18;
  const __bf16* src = qkv + (size_t)(b * 1024 + t) * 3072 + 2048 + kvh * 64;
  float x1 = (float)src[i], x2 = (float)src[i + 32];
  float ang = (float)t * expf((float)i * -0.28782313662425572f);
  float cv = cosf(ang), sv = sinf(ang);
  float o1 = x1 * cv - x2 * sv;
  float o2 = x2 * cv + x1 * sv;
  __bf16 b1 = (__bf16)o1, b2 = (__bf16)o2;
  float f1 = (float)b1, f2 = (float)b2;
  float nrm = f1 * f1 + f2 * f2;
#pragma unroll
  for (int off = 1; off < 32; off <<= 1) nrm += __shfl_xor(nrm, off, 64);
  __bf16* dst = Kr + (((size_t)b * 8 + kvh) * 1024 + t) * 64;
  dst[i] = b1;
  dst[i + 32] = b2;
  if (i == 0) bias2[((size_t)b * 8 + kvh) * 1024 + t] = KBIAS * nrm;
}

// ---------------------------------------------------------------------------
// V transpose: qkv cols [2560,3072) -> VT (b,KV,64,t) bf16
__global__ void vtrans(const __bf16* __restrict__ qkv,
                       __bf16* __restrict__ VT) {
  __shared__ __bf16 tile[64][65];
  int tt = blockIdx.x, bkv = blockIdx.y;
  int b = bkv >> 3, kv = bkv & 7;
  int tl = threadIdx.x >> 6, d = threadIdx.x & 63;
#pragma unroll
  for (int rr = 0; rr < 16; ++rr) {
    int t_local = rr * 4 + tl;
    tile[t_local][d] =
        qkv[(size_t)(b * 1024 + tt * 64 + t_local) * 3072 + 2560 + kv * 64 + d];
  }
  __syncthreads();
#pragma unroll
  for (int rr = 0; rr < 16; ++rr) {
    int d_out = rr * 4 + tl;
    VT[((size_t)(b * 8 + kv) * 64 + d_out) * 1024 + tt * 64 + d] =
        tile[d][d_out];
  }
}

// ---------------------------------------------------------------------------
// Flash attention, conformal scores, no online max (scores bounded), S^T and
// O^T formulations. Software-pipelined K/V staging: double-buffered LDS,
// RAW s_barrier (no vmcnt drain) + manual fine-grained s_waitcnt vmcnt(8) so
// the next tile's global_load_lds batch stays in flight across compute
// (AITER-style K-loop; FIFO vmcnt semantics per m135).
// grid: (32 heads, 8 qtiles reversed, 4 batch), 256 threads.
__global__ __launch_bounds__(256, 2) void attn_kernel(
    const __bf16* __restrict__ Q, const __bf16* __restrict__ Kc,
    const __bf16* __restrict__ VT, const float* __restrict__ bias2,
    __bf16* __restrict__ Y) {
  const int T = 1024;
  int h = blockIdx.x, qt = 7 - blockIdx.y, b = blockIdx.z;
  int kv = h >> 2;
  int tid = threadIdx.x;
  int wave = tid >> 6, lane = tid & 63;
  int quad = lane >> 4, l16 = lane & 15;

  __shared__ __bf16 KsA[2][8 * 128 * 8];  // 2 x 16KB [d-chunk][key][8]
  __shared__ __bf16 VsA[2][16 * 64 * 8];  // 2 x 16KB [key-chunk][d][8]
  __shared__ __bf16 Ps[4][8 * 32 * 8];    // 16KB: 4KB/wave [cp][qslot][8]

  const __bf16* Qb = Q + (((size_t)b * 32 + h) * T + qt * 128 + wave * 32) * 64;
  const __bf16* Kb = Kc + ((size_t)b * 8 + kv) * T * 64;
  const __bf16* Vb = VT + ((size_t)b * 8 + kv) * 64 * T;
  const float* nb = bias2 + ((size_t)b * 8 + kv) * T;
  __bf16* Pw = &Ps[wave][0];

  // Q B-frags (n=q=l16(+16nt), k=d=kd*32+quad*8+j), held all kernel
  bf16x8 qf[2][2];
#pragma unroll
  for (int nt = 0; nt < 2; ++nt)
#pragma unroll
    for (int kd = 0; kd < 2; ++kd)
      qf[nt][kd] =
          *(const bf16x8*)(Qb + (size_t)(nt * 16 + l16) * 64 + kd * 32 + quad * 8);

  bf16x8 onesf;
#pragma unroll
  for (int u = 0; u < 8; ++u) onesf[u] = (__bf16)1.0f;

  f32x4 oacc[2][4] = {};
  f32x4 lacc[2] = {};

  // ---- stage helper: wave w stages its 8 chunks of tile (k0) into buf
#define STAGE_TILE(k0_, buf_)                                                 \
  {                                                                           \
    _Pragma("unroll") for (int u = 0; u < 8; ++u) {                           \
      int t = wave * 8 + u;                                                   \
      if (t < 16) {                                                           \
        int c = t >> 1, kh = t & 1;                                           \
        LDS_ASYNC16(                                                          \
            Kb + (size_t)((k0_) + kh * 64) * 64 + c * 8 + (size_t)lane * 64,  \
            KsA[buf_] + c * 1024 + kh * 512);                                 \
      } else {                                                                \
        int c = t - 16;                                                       \
        LDS_ASYNC16(Vb + (size_t)lane * T + (k0_) + c * 8,                    \
                    VsA[buf_] + c * 512);                                     \
      }                                                                       \
    }                                                                         \
  }

  STAGE_TILE(0, 0);  // prologue: tile 0 -> buf 0

  for (int j = 0; j <= qt; ++j) {
    int k0 = j * 128;
    int cur = j & 1;
    bool diag = (j == qt);

    // bias loads for tile j (issued before the prefetch batch: FIFO-safe)
    f32x4 bv[8];
#pragma unroll
    for (int mt = 0; mt < 8; ++mt)
      bv[mt] = *(const f32x4*)(nb + k0 + mt * 16 + quad * 4);

    if (j < qt) {
      STAGE_TILE(k0 + 128, cur ^ 1);  // prefetch next tile, stays in flight
      asm volatile("s_waitcnt vmcnt(8)" ::: "memory");  // tile j complete
    } else {
      asm volatile("s_waitcnt vmcnt(0)" ::: "memory");
    }
    __builtin_amdgcn_s_barrier();  // raw: no drain, all waves' tile j visible

    const __bf16* Ksc = KsA[cur];
    const __bf16* Vsc = VsA[cur];

    // ---- S^T = K.Q^T, acc initialized to the per-key bias
    f32x4 sacc[8][2];
#pragma unroll
    for (int mt = 0; mt < 8; ++mt) {
      sacc[mt][0] = bv[mt];
      sacc[mt][1] = bv[mt];
    }
#pragma unroll
    for (int kd = 0; kd < 2; ++kd)
#pragma unroll
      for (int mt = 0; mt < 8; ++mt) {
        bf16x8 kf =
            *(const bf16x8*)(Ksc + (kd * 4 + quad) * 1024 + (mt * 16 + l16) * 8);
        sacc[mt][0] = MFMA16(kf, qf[0][kd], sacc[mt][0]);
        sacc[mt][1] = MFMA16(kf, qf[1][kd], sacc[mt][1]);
      }

    if (diag) {  // causal mask, diagonal tile only
#pragma unroll
      for (int mt = 0; mt < 8; ++mt)
#pragma unroll
        for (int nt = 0; nt < 2; ++nt)
#pragma unroll
          for (int r = 0; r < 4; ++r) {
            int key = mt * 16 + quad * 4 + r;
            int ql = wave * 32 + nt * 16 + l16;
            if (key > ql) sacc[mt][nt][r] = -1e30f;
          }
    }

    // ---- two 64-key halves: exp2 -> Ps -> O^T += V^T.P, l += 1.P
#pragma unroll
    for (int kh = 0; kh < 2; ++kh) {
#pragma unroll
      for (int mh = 0; mh < 4; ++mh) {
        int mt = 4 * kh + mh;
        int cp = 2 * mh + (quad >> 1);
        int halfo = (quad & 1) * 4;
#pragma unroll
        for (int nt = 0; nt < 2; ++nt) {
          bf16x4v pk;
#pragma unroll
          for (int r = 0; r < 4; ++r) pk[r] = (__bf16)EXP2F(sacc[mt][nt][r]);
          int qs = ((nt * 16 + l16) + 2 * cp) & 31;
          *(bf16x4v*)(Pw + cp * 256 + qs * 8 + halfo) = pk;
        }
      }
#pragma unroll
      for (int kil = 0; kil < 2; ++kil) {
        int cp = 4 * kil + quad;
        bf16x8 pf0 = *(const bf16x8*)(Pw + cp * 256 + ((l16 + 2 * cp) & 31) * 8);
        bf16x8 pf1 =
            *(const bf16x8*)(Pw + cp * 256 + ((16 + l16 + 2 * cp) & 31) * 8);
        lacc[0] = MFMA16(onesf, pf0, lacc[0]);
        lacc[1] = MFMA16(onesf, pf1, lacc[1]);
        int s = 2 * kh + kil;
#pragma unroll
        for (int dt = 0; dt < 4; ++dt) {
          bf16x8 vf = *(const bf16x8*)(Vsc + (4 * s + quad) * 512 +
                                       (dt * 16 + l16) * 8);
          oacc[0][dt] = MFMA16(vf, pf0, oacc[0][dt]);
          oacc[1][dt] = MFMA16(vf, pf1, oacc[1][dt]);
        }
      }
    }
    __builtin_amdgcn_s_barrier();  // raw: all waves done reading buf[cur]
  }

  // ---- epilogue: O^T C-layout (rows=d, cols=q): per-lane l, packed stores
#pragma unroll
  for (int nt = 0; nt < 2; ++nt) {
    float linv = 1.0f / lacc[nt][0];
    __bf16* Yr =
        Y + (((size_t)b * T + qt * 128 + wave * 32 + nt * 16 + l16) * 32 + h) * 64;
#pragma unroll
    for (int dt = 0; dt < 4; ++dt) {
      bf16x4v ov;
#pragma unroll
      for (int r = 0; r < 4; ++r) ov[r] = (__bf16)(oacc[nt][dt][r] * linv);
      *(bf16x4v*)(Yr + dt * 16 + quad * 4) = ov;
    }
  }
#undef STAGE_TILE
}

// ---------------------------------------------------------------------------
extern "C" void kernel_launch(void* const* d_in, const int* in_sizes, int n_in,
                              void* d_out, int out_size, void* d_ws,
                              size_t ws_size, hipStream_t stream) {
  const float* x = (const float*)d_in[0];
  const float* Wq = (const float*)d_in[1];
  const float* Wk = (const float*)d_in[2];
  const float* Wv = (const float*)d_in[3];
  const float* Wo = (const float*)d_in[4];
  float* out = (float*)d_out;

  char* ws = (char*)d_ws;
  __bf16* xb = (__bf16*)(ws);                            // 16.8MB, reused as Qr
  __bf16* W1T = (__bf16*)(ws + 16777216);                // 12.6MB, reused as WoT
  __bf16* qkv = (__bf16*)(ws + 16777216 + 12582912);     // 25.2MB, reused as y
  char* d4 = ws + 16777216 + 12582912 + 25165824;
  __bf16* Kr = (__bf16*)(d4);
  __bf16* VT = (__bf16*)(d4 + 4194304);
  float* bias2 = (float*)(d4 + 8388608);
  __bf16* Qr = xb;
  __bf16* WoT = W1T;
  __bf16* y = qkv;

  cast_bf16<<<8192, 256, 0, stream>>>(x, xb, 2097152);
  wtrans<<<dim3(32, 32), 256, 0, stream>>>(Wq, 2048, W1T, 2048);
  wtrans<<<dim3(32, 8), 256, 0, stream>>>(Wk, 512, W1T + 2048 * 2048, 2048);
  wtrans<<<dim3(32, 8), 256, 0, stream>>>(Wv, 512, W1T + 2560 * 2048, 2048);
  gemm_bt<1><<<dim3(24, 32), 256, 0, stream>>>(xb, W1T, qkv, 4096, 3072, 2048);
  rope_q_kernel<<<16384, 256, 0, stream>>>(qkv, Qr);
  rope_k_kernel<<<4096, 256, 0, stream>>>(qkv, Kr, bias2);
  vtrans<<<dim3(16, 32), 256, 0, stream>>>(qkv, VT);
  wtrans<<<dim3(32, 32), 256, 0, stream>>>(Wo, 2048, WoT, 2048);
  attn_kernel<<<dim3(32, 8, 4), 256, 0, stream>>>(Qr, Kr, VT, bias2, y);
  gemm_bt<0><<<dim3(16, 32), 256, 0, stream>>>(y, WoT, out, 4096, 2048, 2048);
}

// Round 5
// 286.395 us; speedup vs baseline: 1.8372x; 1.1077x over previous
//
#include <hip/hip_runtime.h>

typedef __bf16 bf16x8 __attribute__((ext_vector_type(8)));
typedef __bf16 bf16x4v __attribute__((ext_vector_type(4)));
typedef float f32x4 __attribute__((ext_vector_type(4)));

#define LDS_ASYNC16(g, l)                                            \
  __builtin_amdgcn_global_load_lds(                                  \
      (__attribute__((address_space(1))) void*)(g),                  \
      (__attribute__((address_space(3))) void*)(l), 16, 0, 0)

#define MFMA16(a, b, c) __builtin_amdgcn_mfma_f32_16x16x32_bf16(a, b, c, 0, 0, 0)

#if __has_builtin(__builtin_amdgcn_exp2f)
#define EXP2F(x) __builtin_amdgcn_exp2f(x)
#else
#define EXP2F(x) exp2f(x)
#endif

// log2(e)/8 and -log2(e)/16: scores computed directly in log2 domain.
#define QSCALE 0.18033688011112042f
#define KBIAS -0.09016844005556021f
#define LN1E4_32 0.28782313662425572f  // ln(10000)/32

// ---------------------------------------------------------------------------
// cast fp32 -> bf16, 4 elems/thread
__global__ void cast_bf16(const float* __restrict__ x, __bf16* __restrict__ y,
                          int n4) {
  int i = blockIdx.x * 256 + threadIdx.x;
  if (i < n4) {
    float4 v = ((const float4*)x)[i];
    bf16x4v o;
    o[0] = (__bf16)v.x; o[1] = (__bf16)v.y; o[2] = (__bf16)v.z; o[3] = (__bf16)v.w;
    ((bf16x4v*)y)[i] = o;
  }
}

// ---------------------------------------------------------------------------
// batched transpose+cast of all 4 weights: Wq|Wk|Wv -> W1T (3072x2048),
// Wo -> WoT (2048x2048). grid (32, 80).
__global__ void wtrans_all(const float* __restrict__ Wq,
                           const float* __restrict__ Wk,
                           const float* __restrict__ Wv,
                           const float* __restrict__ Wo,
                           __bf16* __restrict__ W1T, __bf16* __restrict__ WoT) {
  __shared__ float tile[64][65];
  int gy = blockIdx.y;
  const float* src;
  int srcld, n0;
  __bf16* dst;
  if (gy < 32) {
    src = Wq; srcld = 2048; dst = W1T; n0 = gy * 64;
  } else if (gy < 40) {
    src = Wk; srcld = 512; dst = W1T + (size_t)2048 * 2048; n0 = (gy - 32) * 64;
  } else if (gy < 48) {
    src = Wv; srcld = 512; dst = W1T + (size_t)2560 * 2048; n0 = (gy - 40) * 64;
  } else {
    src = Wo; srcld = 2048; dst = WoT; n0 = (gy - 48) * 64;
  }
  int k0 = blockIdx.x * 64;
  int tl = threadIdx.x >> 6, c = threadIdx.x & 63;
#pragma unroll
  for (int rr = 0; rr < 16; ++rr) {
    int k = rr * 4 + tl;
    tile[k][c] = src[(size_t)(k0 + k) * srcld + n0 + c];
  }
  __syncthreads();
#pragma unroll
  for (int rr = 0; rr < 16; ++rr) {
    int n = rr * 4 + tl;
    dst[(size_t)(n0 + n) * 2048 + k0 + c] = (__bf16)tile[c][n];
  }
}

// ---------------------------------------------------------------------------
// m97-style bf16 GEMM: C(MxN) = A(MxK) * B^T where B is (N x K) row-major.
template <int OUTBF16>
__global__ __launch_bounds__(256) void gemm_bt(const __bf16* __restrict__ A,
                                               const __bf16* __restrict__ B,
                                               void* __restrict__ Cout, int M,
                                               int N, int K) {
  __shared__ __bf16 As[128 * 32];
  __shared__ __bf16 Bs[128 * 32];
  int tid = threadIdx.x;
  int wave = tid >> 6, lane = tid & 63;
  int quad = lane >> 4, l16 = lane & 15;
  int wm = (wave & 1) * 64, wn = (wave >> 1) * 64;
  int tm = blockIdx.y * 128, tn = blockIdx.x * 128;

  f32x4 acc[4][4] = {};

  int srow = tid >> 2;
  int scol = (tid & 3) * 8;
  const __bf16* gA = A + (size_t)(tm + srow) * K + scol;
  const __bf16* gB = B + (size_t)(tn + srow) * K + scol;
  __bf16* lA0 = As + wave * 512;
  __bf16* lA1 = As + 2048 + wave * 512;
  __bf16* lB0 = Bs + wave * 512;
  __bf16* lB1 = Bs + 2048 + wave * 512;
  size_t stepA = (size_t)64 * K;

  for (int k0 = 0; k0 < K; k0 += 32) {
    LDS_ASYNC16(gA, lA0);
    LDS_ASYNC16(gA + stepA, lA1);
    LDS_ASYNC16(gB, lB0);
    LDS_ASYNC16(gB + stepA, lB1);
    gA += 32;
    gB += 32;
    __syncthreads();
    bf16x8 af[4], bfr[4];
#pragma unroll
    for (int mt = 0; mt < 4; ++mt)
      af[mt] = *(const bf16x8*)(As + (wm + mt * 16 + l16) * 32 + quad * 8);
#pragma unroll
    for (int nt = 0; nt < 4; ++nt)
      bfr[nt] = *(const bf16x8*)(Bs + (wn + nt * 16 + l16) * 32 + quad * 8);
#pragma unroll
    for (int mt = 0; mt < 4; ++mt)
#pragma unroll
      for (int nt = 0; nt < 4; ++nt)
        acc[mt][nt] = MFMA16(af[mt], bfr[nt], acc[mt][nt]);
    __syncthreads();
  }
  int r0 = tm + wm + quad * 4;
  int c0 = tn + wn + l16;
#pragma unroll
  for (int mt = 0; mt < 4; ++mt)
#pragma unroll
    for (int nt = 0; nt < 4; ++nt)
#pragma unroll
      for (int r = 0; r < 4; ++r) {
        size_t idx = (size_t)(r0 + mt * 16 + r) * N + (c0 + nt * 16);
        if (OUTBF16)
          ((__bf16*)Cout)[idx] = (__bf16)acc[mt][nt][r];
        else
          ((float*)Cout)[idx] = acc[mt][nt][r];
      }
}

// ---------------------------------------------------------------------------
// QKV GEMM with fused RoPE / conformal-bias / V-transpose epilogue.
// C = x_bf16 (4096x2048) * W1T^T (3072x2048^T); each wave's 64-col span is
// exactly one head, and the RoPE partner of col i (i+32) is in the SAME lane
// (nt vs nt+2), so rotation is in-register. |k|^2 is 4 in-quad shfl_xor.
// blockIdx.x: 0..15 -> Q (RoPE, *log2e/8), 16..19 -> K (RoPE + bias),
// 20..23 -> V (direct transposed store to VT).
__global__ __launch_bounds__(256) void gemm_qkv(
    const __bf16* __restrict__ A, const __bf16* __restrict__ B,
    __bf16* __restrict__ Qr, __bf16* __restrict__ Kr, __bf16* __restrict__ VT,
    float* __restrict__ bias2) {
  const int K = 2048;
  __shared__ __bf16 As[128 * 32];
  __shared__ __bf16 Bs[128 * 32];
  int tid = threadIdx.x;
  int wave = tid >> 6, lane = tid & 63;
  int quad = lane >> 4, l16 = lane & 15;
  int wm = (wave & 1) * 64, wn = (wave >> 1) * 64;
  int tm = blockIdx.y * 128, tn = blockIdx.x * 128;

  f32x4 acc[4][4] = {};

  int srow = tid >> 2;
  int scol = (tid & 3) * 8;
  const __bf16* gA = A + (size_t)(tm + srow) * K + scol;
  const __bf16* gB = B + (size_t)(tn + srow) * K + scol;
  __bf16* lA0 = As + wave * 512;
  __bf16* lA1 = As + 2048 + wave * 512;
  __bf16* lB0 = Bs + wave * 512;
  __bf16* lB1 = Bs + 2048 + wave * 512;
  size_t stepA = (size_t)64 * K;

  for (int k0 = 0; k0 < K; k0 += 32) {
    LDS_ASYNC16(gA, lA0);
    LDS_ASYNC16(gA + stepA, lA1);
    LDS_ASYNC16(gB, lB0);
    LDS_ASYNC16(gB + stepA, lB1);
    gA += 32;
    gB += 32;
    __syncthreads();
    bf16x8 af[4], bfr[4];
#pragma unroll
    for (int mt = 0; mt < 4; ++mt)
      af[mt] = *(const bf16x8*)(As + (wm + mt * 16 + l16) * 32 + quad * 8);
#pragma unroll
    for (int nt = 0; nt < 4; ++nt)
      bfr[nt] = *(const bf16x8*)(Bs + (wn + nt * 16 + l16) * 32 + quad * 8);
#pragma unroll
    for (int mt = 0; mt < 4; ++mt)
#pragma unroll
      for (int nt = 0; nt < 4; ++nt)
        acc[mt][nt] = MFMA16(af[mt], bfr[nt], acc[mt][nt]);
    __syncthreads();
  }

  int r0 = tm + wm + quad * 4;  // global row = b*1024 + t
  int c0 = tn + wn;             // 64-aligned: one head per wave

  if (blockIdx.x < 20) {
    // ---- Q or K: RoPE rotation in-register
    bool isQ = (blockIdx.x < 16);
    // i-values this lane holds: l16 (pairs nt0/nt2) and 16+l16 (nt1/nt3)
    float invf0 = expf((float)l16 * -LN1E4_32);
    float invf1 = expf((float)(l16 + 16) * -LN1E4_32);
    int h = isQ ? (c0 >> 6) : ((c0 - 2048) >> 6);
    __bf16* base = isQ ? Qr : Kr;
    int nh = isQ ? 32 : 8;
#pragma unroll
    for (int mt = 0; mt < 4; ++mt) {
      float nsq[4];
#pragma unroll
      for (int r = 0; r < 4; ++r) {
        int row = r0 + mt * 16 + r;
        int t = row & 1023, b = row >> 10;
        float tf = (float)t;
        float a0 = tf * invf0, a1 = tf * invf1;
        float s0, c0f, s1, c1f;
        sincosf(a0, &s0, &c0f);
        sincosf(a1, &s1, &c1f);
        float oa = acc[mt][0][r] * c0f - acc[mt][2][r] * s0;  // d = l16
        float oc = acc[mt][2][r] * c0f + acc[mt][0][r] * s0;  // d = 32+l16
        float ob = acc[mt][1][r] * c1f - acc[mt][3][r] * s1;  // d = 16+l16
        float od = acc[mt][3][r] * c1f + acc[mt][1][r] * s1;  // d = 48+l16
        if (isQ) {
          oa *= QSCALE; ob *= QSCALE; oc *= QSCALE; od *= QSCALE;
        }
        __bf16 ba = (__bf16)oa, bb = (__bf16)ob, bc = (__bf16)oc,
               bd = (__bf16)od;
        __bf16* dst = base + (((size_t)b * nh + h) * 1024 + t) * 64;
        dst[l16] = ba;
        dst[16 + l16] = bb;
        dst[32 + l16] = bc;
        dst[48 + l16] = bd;
        // |k|^2 from the bf16-rounded values (consistent with q.k in attn)
        float fa = (float)ba, fb = (float)bb, fc = (float)bc, fd = (float)bd;
        nsq[r] = fa * fa + fb * fb + fc * fc + fd * fd;
      }
      if (!isQ) {
#pragma unroll
        for (int r = 0; r < 4; ++r) {
          float nl = nsq[r];
          nl += __shfl_xor(nl, 1);
          nl += __shfl_xor(nl, 2);
          nl += __shfl_xor(nl, 4);
          nl += __shfl_xor(nl, 8);
          if (l16 == 0) {
            int row = r0 + mt * 16 + r;
            int t = row & 1023, b = row >> 10;
            bias2[((size_t)b * 8 + h) * 1024 + t] = KBIAS * nl;
          }
        }
      }
    }
  } else {
    // ---- V: store transposed VT (b,kv,64,t); 4 rows = 4 consecutive t
    int kvh = (c0 - 2560) >> 6;
#pragma unroll
    for (int mt = 0; mt < 4; ++mt) {
      int rowb = r0 + mt * 16;  // 4-aligned, same b for r 0..3
      int t = rowb & 1023, b = rowb >> 10;
#pragma unroll
      for (int nt = 0; nt < 4; ++nt) {
        int d = nt * 16 + l16;
        bf16x4v ov;
#pragma unroll
        for (int r = 0; r < 4; ++r) ov[r] = (__bf16)acc[mt][nt][r];
        *(bf16x4v*)(VT + ((size_t)(b * 8 + kvh) * 64 + d) * 1024 + t) = ov;
      }
    }
  }
}

// ---------------------------------------------------------------------------
// Flash attention, conformal scores, no online max (scores bounded), S^T and
// O^T formulations, software-pipelined K/V staging (raw s_barrier + manual
// s_waitcnt vmcnt(8): next tile's global_load_lds stays in flight).
// grid: (32 heads, 8 qtiles reversed, 4 batch), 256 threads.
__global__ __launch_bounds__(256, 2) void attn_kernel(
    const __bf16* __restrict__ Q, const __bf16* __restrict__ Kc,
    const __bf16* __restrict__ VT, const float* __restrict__ bias2,
    __bf16* __restrict__ Y) {
  const int T = 1024;
  int h = blockIdx.x, qt = 7 - blockIdx.y, b = blockIdx.z;
  int kv = h >> 2;
  int tid = threadIdx.x;
  int wave = tid >> 6, lane = tid & 63;
  int quad = lane >> 4, l16 = lane & 15;

  __shared__ __bf16 KsA[2][8 * 128 * 8];  // 2 x 16KB [d-chunk][key][8]
  __shared__ __bf16 VsA[2][16 * 64 * 8];  // 2 x 16KB [key-chunk][d][8]
  __shared__ __bf16 Ps[4][8 * 32 * 8];    // 16KB: 4KB/wave [cp][qslot][8]

  const __bf16* Qb = Q + (((size_t)b * 32 + h) * T + qt * 128 + wave * 32) * 64;
  const __bf16* Kb = Kc + ((size_t)b * 8 + kv) * T * 64;
  const __bf16* Vb = VT + ((size_t)b * 8 + kv) * 64 * T;
  const float* nb = bias2 + ((size_t)b * 8 + kv) * T;
  __bf16* Pw = &Ps[wave][0];

  bf16x8 qf[2][2];
#pragma unroll
  for (int nt = 0; nt < 2; ++nt)
#pragma unroll
    for (int kd = 0; kd < 2; ++kd)
      qf[nt][kd] =
          *(const bf16x8*)(Qb + (size_t)(nt * 16 + l16) * 64 + kd * 32 + quad * 8);

  bf16x8 onesf;
#pragma unroll
  for (int u = 0; u < 8; ++u) onesf[u] = (__bf16)1.0f;

  f32x4 oacc[2][4] = {};
  f32x4 lacc[2] = {};

#define STAGE_TILE(k0_, buf_)                                                 \
  {                                                                           \
    _Pragma("unroll") for (int u = 0; u < 8; ++u) {                           \
      int t = wave * 8 + u;                                                   \
      if (t < 16) {                                                           \
        int c = t >> 1, kh = t & 1;                                           \
        LDS_ASYNC16(                                                          \
            Kb + (size_t)((k0_) + kh * 64) * 64 + c * 8 + (size_t)lane * 64,  \
            KsA[buf_] + c * 1024 + kh * 512);                                 \
      } else {                                                                \
        int c = t - 16;                                                       \
        LDS_ASYNC16(Vb + (size_t)lane * T + (k0_) + c * 8,                    \
                    VsA[buf_] + c * 512);                                     \
      }                                                                       \
    }                                                                         \
  }

  STAGE_TILE(0, 0);

  for (int j = 0; j <= qt; ++j) {
    int k0 = j * 128;
    int cur = j & 1;
    bool diag = (j == qt);

    f32x4 bv[8];
#pragma unroll
    for (int mt = 0; mt < 8; ++mt)
      bv[mt] = *(const f32x4*)(nb + k0 + mt * 16 + quad * 4);

    if (j < qt) {
      STAGE_TILE(k0 + 128, cur ^ 1);
      asm volatile("s_waitcnt vmcnt(8)" ::: "memory");
    } else {
      asm volatile("s_waitcnt vmcnt(0)" ::: "memory");
    }
    __builtin_amdgcn_s_barrier();

    const __bf16* Ksc = KsA[cur];
    const __bf16* Vsc = VsA[cur];

    f32x4 sacc[8][2];
#pragma unroll
    for (int mt = 0; mt < 8; ++mt) {
      sacc[mt][0] = bv[mt];
      sacc[mt][1] = bv[mt];
    }
#pragma unroll
    for (int kd = 0; kd < 2; ++kd)
#pragma unroll
      for (int mt = 0; mt < 8; ++mt) {
        bf16x8 kf =
            *(const bf16x8*)(Ksc + (kd * 4 + quad) * 1024 + (mt * 16 + l16) * 8);
        sacc[mt][0] = MFMA16(kf, qf[0][kd], sacc[mt][0]);
        sacc[mt][1] = MFMA16(kf, qf[1][kd], sacc[mt][1]);
      }

    if (diag) {
#pragma unroll
      for (int mt = 0; mt < 8; ++mt)
#pragma unroll
        for (int nt = 0; nt < 2; ++nt)
#pragma unroll
          for (int r = 0; r < 4; ++r) {
            int key = mt * 16 + quad * 4 + r;
            int ql = wave * 32 + nt * 16 + l16;
            if (key > ql) sacc[mt][nt][r] = -1e30f;
          }
    }

#pragma unroll
    for (int kh = 0; kh < 2; ++kh) {
#pragma unroll
      for (int mh = 0; mh < 4; ++mh) {
        int mt = 4 * kh + mh;
        int cp = 2 * mh + (quad >> 1);
        int halfo = (quad & 1) * 4;
#pragma unroll
        for (int nt = 0; nt < 2; ++nt) {
          bf16x4v pk;
#pragma unroll
          for (int r = 0; r < 4; ++r) pk[r] = (__bf16)EXP2F(sacc[mt][nt][r]);
          int qs = ((nt * 16 + l16) + 2 * cp) & 31;
          *(bf16x4v*)(Pw + cp * 256 + qs * 8 + halfo) = pk;
        }
      }
#pragma unroll
      for (int kil = 0; kil < 2; ++kil) {
        int cp = 4 * kil + quad;
        bf16x8 pf0 = *(const bf16x8*)(Pw + cp * 256 + ((l16 + 2 * cp) & 31) * 8);
        bf16x8 pf1 =
            *(const bf16x8*)(Pw + cp * 256 + ((16 + l16 + 2 * cp) & 31) * 8);
        lacc[0] = MFMA16(onesf, pf0, lacc[0]);
        lacc[1] = MFMA16(onesf, pf1, lacc[1]);
        int s = 2 * kh + kil;
#pragma unroll
        for (int dt = 0; dt < 4; ++dt) {
          bf16x8 vf = *(const bf16x8*)(Vsc + (4 * s + quad) * 512 +
                                       (dt * 16 + l16) * 8);
          oacc[0][dt] = MFMA16(vf, pf0, oacc[0][dt]);
          oacc[1][dt] = MFMA16(vf, pf1, oacc[1][dt]);
        }
      }
    }
    __builtin_amdgcn_s_barrier();
  }

#pragma unroll
  for (int nt = 0; nt < 2; ++nt) {
    float linv = 1.0f / lacc[nt][0];
    __bf16* Yr =
        Y + (((size_t)b * T + qt * 128 + wave * 32 + nt * 16 + l16) * 32 + h) * 64;
#pragma unroll
    for (int dt = 0; dt < 4; ++dt) {
      bf16x4v ov;
#pragma unroll
      for (int r = 0; r < 4; ++r) ov[r] = (__bf16)(oacc[nt][dt][r] * linv);
      *(bf16x4v*)(Yr + dt * 16 + quad * 4) = ov;
    }
  }
#undef STAGE_TILE
}

// ---------------------------------------------------------------------------
extern "C" void kernel_launch(void* const* d_in, const int* in_sizes, int n_in,
                              void* d_out, int out_size, void* d_ws,
                              size_t ws_size, hipStream_t stream) {
  const float* x = (const float*)d_in[0];
  const float* Wq = (const float*)d_in[1];
  const float* Wk = (const float*)d_in[2];
  const float* Wv = (const float*)d_in[3];
  const float* Wo = (const float*)d_in[4];
  float* out = (float*)d_out;

  char* ws = (char*)d_ws;
  __bf16* xb = (__bf16*)(ws);                         // 16.8MB; later y
  __bf16* W1T = (__bf16*)(ws + 16777216);             // 12.6MB
  __bf16* WoT = (__bf16*)(ws + 16777216 + 12582912);  // 8.4MB
  char* d4 = ws + 16777216 + 12582912 + 8388608;
  __bf16* Qr = (__bf16*)(d4);                   // 16.8MB
  __bf16* Kr = (__bf16*)(d4 + 16777216);        // 4.2MB
  __bf16* VT = (__bf16*)(d4 + 16777216 + 4194304);
  float* bias2 = (float*)(d4 + 16777216 + 8388608);
  __bf16* y = xb;  // xb dead after gemm_qkv

  cast_bf16<<<8192, 256, 0, stream>>>(x, xb, 2097152);
  wtrans_all<<<dim3(32, 80), 256, 0, stream>>>(Wq, Wk, Wv, Wo, W1T, WoT);
  gemm_qkv<<<dim3(24, 32), 256, 0, stream>>>(xb, W1T, Qr, Kr, VT, bias2);
  attn_kernel<<<dim3(32, 8, 4), 256, 0, stream>>>(Qr, Kr, VT, bias2, y);
  gemm_bt<0><<<dim3(16, 32), 256, 0, stream>>>(y, WoT, out, 4096, 2048, 2048);
}